// Round 4
// baseline (226.222 us; speedup 1.0000x reference)
//
#include <hip/hip_runtime.h>
#include <hip/hip_bf16.h>

// Problem constants: B=32768, IN=64, H=256, D=16, C=8, K=64, HS=8
// Output layout (floats, concatenated in return order):
#define O0 0ull          // K_chart   [32768]
#define O1 32768ull      // K_code    [32768]
#define O2 65536ull      // z_n       [32768][16]
#define O3 589824ull     // z_tex     [32768][16]
#define O4 1114112ull    // router_weights [32768][8]
#define O5 1376256ull    // z_geo     [32768][16]
#define O6 1900544ull    // vq_loss   [1]
#define O7 1900545ull    // indices   [32768][8]
#define O8 2162689ull    // z_n_all_charts [32768][8][16]
#define O9 6356993ull    // c_bar     [32768][16]

// np-f32 gelu replica: x * (erf(x / f32(sqrt(2))) + 1) / 2, erf via double downcast
__device__ __forceinline__ float gelu_np(float x) {
#pragma clang fp contract(off)
    float t = x / 0x1.6a09e6p+0f;          // f32(sqrt(2))
    float e = (float)erf((double)t);
    float u = e + 1.0f;
    return (x * u) / 2.0f;
}

// Out = gelu_np(seqfma_k(A,W) + bias). A:[32768][K], W:[K][256], Out:[32768][256]
// BLAS-replica: per output element, k-ascending sequential fmaf from 0.
// 64-row tile, 256 threads. In-place safe (block reads only its own rows).
__global__ __launch_bounds__(256) void gemm_gelu_np_k(
    const float* A, const float* __restrict__ W,
    const float* __restrict__ bias, float* Out, int K)
{
#pragma clang fp contract(off)
    __shared__ float sA[64][16];
    __shared__ float sB[16][256];
    const int t  = threadIdx.x;
    const int r0 = blockIdx.x * 64;
    const int rg = t >> 6;
    const int cg = t & 63;

    float acc[16][4];
#pragma unroll
    for (int i = 0; i < 16; ++i) { acc[i][0]=0.f; acc[i][1]=0.f; acc[i][2]=0.f; acc[i][3]=0.f; }

    const int rs = t >> 2;
    const int cs = (t & 3) * 4;
    for (int k0 = 0; k0 < K; k0 += 16) {
        *(float4*)&sA[rs][cs] = *(const float4*)(A + (size_t)(r0 + rs) * K + k0 + cs);
        const float* srcW = W + (size_t)k0 * 256;
#pragma unroll
        for (int i = 0; i < 4; ++i) {
            int u = (t + 256 * i) * 4;
            *(float4*)(&sB[0][0] + u) = *(const float4*)(srcW + u);
        }
        __syncthreads();
        // k ascending, one accumulator per element, fmaf chain (BLAS order)
#pragma unroll
        for (int kk = 0; kk < 16; ++kk) {
            float4 b = *(float4*)&sB[kk][cg * 4];
#pragma unroll
            for (int rr = 0; rr < 16; ++rr) {
                float a = sA[rg * 16 + rr][kk];
                acc[rr][0] = fmaf(a, b.x, acc[rr][0]);
                acc[rr][1] = fmaf(a, b.y, acc[rr][1]);
                acc[rr][2] = fmaf(a, b.z, acc[rr][2]);
                acc[rr][3] = fmaf(a, b.w, acc[rr][3]);
            }
        }
        __syncthreads();
    }
    float4 bvf = *(const float4*)(bias + cg * 4);
#pragma unroll
    for (int rr = 0; rr < 16; ++rr) {
        float4 o;
        o.x = gelu_np(acc[rr][0] + bvf.x);
        o.y = gelu_np(acc[rr][1] + bvf.y);
        o.z = gelu_np(acc[rr][2] + bvf.z);
        o.w = gelu_np(acc[rr][3] + bvf.w);
        *(float4*)(Out + (size_t)(r0 + rg * 16 + rr) * 256 + cg * 4) = o;
    }
}

// v = seqfma_k(f2,Wv) + bv, f32, BLAS order. thread=(row,d), 16 rows/block.
__global__ __launch_bounds__(256) void v_np_k(
    const float* __restrict__ f2, const float* __restrict__ Wv,
    const float* __restrict__ bv, float* __restrict__ vout)
{
#pragma clang fp contract(off)
    __shared__ float sWvT[16][260];
    const int t = threadIdx.x;
    for (int i = t; i < 4096; i += 256) {
        int d = i & 15, k = i >> 4;
        sWvT[d][k] = Wv[i];
    }
    __syncthreads();
    const int d   = t & 15;
    const int row = blockIdx.x * 16 + (t >> 4);
    float acc = 0.f;
    const float* fr = f2 + (size_t)row * 256;
#pragma unroll 4
    for (int k = 0; k < 256; k += 4) {
        float4 f = *(const float4*)(fr + k);
        acc = fmaf(f.x, sWvT[d][k + 0], acc);
        acc = fmaf(f.y, sWvT[d][k + 1], acc);
        acc = fmaf(f.z, sWvT[d][k + 2], acc);
        acc = fmaf(f.w, sWvT[d][k + 3], acc);
    }
    vout[(size_t)row * 16 + d] = acc + bv[d];
}

// Per-row atlas, np-f32 replica arithmetic. thread=(row,chart), 32 rows/block.
__global__ __launch_bounds__(256) void atlas_np_k(
    const float* __restrict__ vbuf, const float* __restrict__ cc,
    const float* __restrict__ cb,   const float* __restrict__ sfW1,
    const float* __restrict__ sfb1, const float* __restrict__ sfW2,
    const float* __restrict__ sfb2, float* __restrict__ out,
    float* __restrict__ partials)
{
#pragma clang fp contract(off)
    __shared__ float scb[8 * 1284];   // (c,kk,d) at c*1284 + kk*20 + d
    __shared__ float scc[128];
    __shared__ float sW1[128];
    __shared__ float sW2[128];
    __shared__ float sb1[8];
    __shared__ float sb2[16];
    __shared__ float red[4];

    const int t = threadIdx.x;
    for (int i = t; i < 8192; i += 256) {
        int c = i >> 10, rem = i & 1023, kk = rem >> 4, d = rem & 15;
        scb[c * 1284 + kk * 20 + d] = cb[i];
    }
    if (t < 128) { scc[t] = cc[t]; sW1[t] = sfW1[t]; sW2[t] = sfW2[t]; }
    if (t < 8)  sb1[t] = sfb1[t];
    if (t < 16) sb2[t] = sfb2[t];
    __syncthreads();

    const int c    = t & 7;
    const int lane = t & 63;
    const int lb   = lane & ~7;
    const int row  = blockIdx.x * 32 + (t >> 3);

    float v[16];
    {
        const float4* vp = (const float4*)(vbuf + (size_t)row * 16);
        float4 a = vp[0], b = vp[1], g = vp[2], h4 = vp[3];
        v[0]=a.x;  v[1]=a.y;  v[2]=a.z;  v[3]=a.w;
        v[4]=b.x;  v[5]=b.y;  v[6]=b.z;  v[7]=b.w;
        v[8]=g.x;  v[9]=g.y;  v[10]=g.z; v[11]=g.w;
        v[12]=h4.x; v[13]=h4.y; v[14]=h4.z; v[15]=h4.w;
    }

    // scores: sgemm k-seq fma over d, then /4 (exact)
    float score = 0.f;
#pragma unroll
    for (int d = 0; d < 16; ++d) score = fmaf(v[d], scc[c * 16 + d], score);
    score = score / 4.0f;

    // softmax: max (exact), exp via double downcast, pairwise-8 scalar-tree sum
    float m = score;
#pragma unroll
    for (int off = 1; off < 8; off <<= 1) m = fmaxf(m, __shfl_xor(m, off));
    float e = (float)exp((double)(score - m));
    float ea[8];
#pragma unroll
    for (int j = 0; j < 8; ++j) ea[j] = __shfl(e, lb + j);
    float s = ((ea[0] + ea[1]) + (ea[2] + ea[3])) + ((ea[4] + ea[5]) + (ea[6] + ea[7]));
    float rw = e / s;

    float rwa[8];
#pragma unroll
    for (int j = 0; j < 8; ++j) rwa[j] = ea[j] / s;

    // K_chart = np.argmax(router_weights): first-wins scan on f32 rw
    float bmv = rwa[0]; int bci = 0;
#pragma unroll
    for (int j = 1; j < 8; ++j) if (rwa[j] > bmv) { bmv = rwa[j]; bci = j; }

    // c_bar: sgemm K=8 seq fma; v_local f32 sub
    float cbar[16], vl[16];
#pragma unroll
    for (int d = 0; d < 16; ++d) {
        float a = 0.f;
#pragma unroll
        for (int j = 0; j < 8; ++j) a = fmaf(rwa[j], scc[j * 16 + d], a);
        cbar[d] = a;
        vl[d]   = v[d] - a;
    }

    // argmin over 64 codes: np dist = pairwise-16 scalar tree of (vl-q)^2, no fma
    const float* cbc = scb + c * 1284;
    float bd = 3.4e38f; int bk = 0; bool first = true;
    for (int kk = 0; kk < 64; ++kk) {
        const float4* q = (const float4*)(cbc + kk * 20);
        float4 q0 = q[0], q1 = q[1], q2 = q[2], q3 = q[3];
        float sq[16];
        float dd;
        dd = vl[0]  - q0.x; sq[0]  = dd * dd;
        dd = vl[1]  - q0.y; sq[1]  = dd * dd;
        dd = vl[2]  - q0.z; sq[2]  = dd * dd;
        dd = vl[3]  - q0.w; sq[3]  = dd * dd;
        dd = vl[4]  - q1.x; sq[4]  = dd * dd;
        dd = vl[5]  - q1.y; sq[5]  = dd * dd;
        dd = vl[6]  - q1.z; sq[6]  = dd * dd;
        dd = vl[7]  - q1.w; sq[7]  = dd * dd;
        dd = vl[8]  - q2.x; sq[8]  = dd * dd;
        dd = vl[9]  - q2.y; sq[9]  = dd * dd;
        dd = vl[10] - q2.z; sq[10] = dd * dd;
        dd = vl[11] - q2.w; sq[11] = dd * dd;
        dd = vl[12] - q3.x; sq[12] = dd * dd;
        dd = vl[13] - q3.y; sq[13] = dd * dd;
        dd = vl[14] - q3.z; sq[14] = dd * dd;
        dd = vl[15] - q3.w; sq[15] = dd * dd;
        float r0_ = sq[0] + sq[8],  r1_ = sq[1] + sq[9];
        float r2_ = sq[2] + sq[10], r3_ = sq[3] + sq[11];
        float r4_ = sq[4] + sq[12], r5_ = sq[5] + sq[13];
        float r6_ = sq[6] + sq[14], r7_ = sq[7] + sq[15];
        float dist = ((r0_ + r1_) + (r2_ + r3_)) + ((r4_ + r5_) + (r6_ + r7_));
        if (first || dist < bd) { bd = dist; bk = kk; first = false; }
    }

    float zq[16];
    {
        const float4* q = (const float4*)(cbc + bk * 20);
        float4 q0 = q[0], q1 = q[1], q2 = q[2], q3 = q[3];
        zq[0]=q0.x;  zq[1]=q0.y;  zq[2]=q0.z;  zq[3]=q0.w;
        zq[4]=q1.x;  zq[5]=q1.y;  zq[6]=q1.z;  zq[7]=q1.w;
        zq[8]=q2.x;  zq[9]=q2.y;  zq[10]=q2.z; zq[11]=q2.w;
        zq[12]=q3.x; zq[13]=q3.y; zq[14]=q3.z; zq[15]=q3.w;
    }

    float del[16];
#pragma unroll
    for (int d = 0; d < 16; ++d) del[d] = vl[d] - zq[d];

    // subnet: sgemm k-seq fma + bias-after + gelu_np, then K=8 fma + bias
    float h[8];
#pragma unroll
    for (int j = 0; j < 8; ++j) {
        float a = 0.f;
#pragma unroll
        for (int d = 0; d < 16; ++d) a = fmaf(del[d], sW1[d * 8 + j], a);
        h[j] = gelu_np(a + sb1[j]);
    }
    float zn[16];
#pragma unroll
    for (int d = 0; d < 16; ++d) {
        float a = 0.f;
#pragma unroll
        for (int j = 0; j < 8; ++j) a = fmaf(h[j], sW2[j * 16 + d], a);
        zn[d] = a + sb2[d];
    }

    // loss: rw * ||vl - zq||^2 (threshold loose; any order)
    float ls = 0.f;
#pragma unroll
    for (int d = 0; d < 16; ++d) ls = fmaf(del[d], del[d], ls);
    ls *= rw;

    // cross-chart sums: np sum over axis=1 (outer axis) = SEQUENTIAL over c,
    // products rounded first. Gather via shuffles; every lane computes all 16.
    float zqb[16], zns[16];
#pragma unroll
    for (int dd = 0; dd < 16; ++dd) {
        float aq = 0.f, an = 0.f;
#pragma unroll
        for (int j = 0; j < 8; ++j) {
            float qv = __shfl(zq[dd], lb + j);
            float nv = __shfl(zn[dd], lb + j);
            float pq = qv * rwa[j];
            float pn = nv * rwa[j];
            aq = aq + pq;
            an = an + pn;
        }
        zqb[dd] = aq;
        zns[dd] = an;
    }

    // stores
    out[O4 + (size_t)row * 8 + c] = rw;
    out[O7 + (size_t)row * 8 + c] = (float)bk;
    {
        float* p = out + O8 + (size_t)row * 128 + c * 16;
#pragma unroll
        for (int d = 0; d < 16; ++d) p[d] = zn[d];
    }
    if (c == 0)   out[O0 + row] = (float)bci;
    if (c == bci) out[O1 + row] = (float)bk;
#pragma unroll
    for (int u = 0; u < 2; ++u) {
        int d = c * 2 + u;
        float zst = vl[d] + (zqb[d] - vl[d]);           // z_q_st np order
        out[O2 + (size_t)row * 16 + d] = zns[d];                    // z_n
        out[O3 + (size_t)row * 16 + d] = (vl[d] - zqb[d]) - zns[d]; // z_tex
        out[O5 + (size_t)row * 16 + d] = (cbar[d] + zst) + zns[d];  // z_geo
        out[O9 + (size_t)row * 16 + d] = cbar[d];                   // c_bar
    }

    // block loss partial (deterministic)
#pragma unroll
    for (int off = 1; off < 64; off <<= 1) ls += __shfl_xor(ls, off);
    if ((t & 63) == 0) red[t >> 6] = ls;
    __syncthreads();
    if (t == 0) partials[blockIdx.x] = red[0] + red[1] + red[2] + red[3];
}

__global__ __launch_bounds__(256) void loss_reduce_k(
    const float* __restrict__ partials, float* __restrict__ out)
{
    __shared__ float sm[256];
    const int t = threadIdx.x;
    float a = 0.f;
    for (int i = t; i < 1024; i += 256) a += partials[i];
    sm[t] = a;
    __syncthreads();
    for (int s2 = 128; s2 > 0; s2 >>= 1) {
        if (t < s2) sm[t] += sm[t + s2];
        __syncthreads();
    }
    if (t == 0) out[O6] = sm[0] * (1.25f / 524288.0f);  // 1.25 / (B*D)
}

extern "C" void kernel_launch(void* const* d_in, const int* in_sizes, int n_in,
                              void* d_out, int out_size, void* d_ws, size_t ws_size,
                              hipStream_t stream) {
    (void)in_sizes; (void)n_in; (void)out_size;
    const float* x    = (const float*)d_in[0];
    const float* W1   = (const float*)d_in[1];
    const float* b1   = (const float*)d_in[2];
    const float* W2   = (const float*)d_in[3];
    const float* b2   = (const float*)d_in[4];
    const float* Wv   = (const float*)d_in[5];
    const float* bv   = (const float*)d_in[6];
    const float* cc   = (const float*)d_in[7];
    const float* cb   = (const float*)d_in[8];
    const float* sfW1 = (const float*)d_in[9];
    const float* sfb1 = (const float*)d_in[10];
    const float* sfW2 = (const float*)d_in[11];
    const float* sfb2 = (const float*)d_in[12];
    float* out = (float*)d_out;

    float* fbuf = (float*)d_ws;                       // [32768][256] f1 then f2 in-place
    float* vbuf = fbuf + (size_t)32768 * 256;         // [32768][16] f32
    float* partials = vbuf + (size_t)32768 * 16;      // [1024]
    if (ws_size < ((size_t)32768 * 256 + (size_t)32768 * 16 + 1024) * 4) return;

    gemm_gelu_np_k<<<512, 256, 0, stream>>>(x,    W1, b1, fbuf, 64);
    gemm_gelu_np_k<<<512, 256, 0, stream>>>(fbuf, W2, b2, fbuf, 256);
    v_np_k        <<<2048, 256, 0, stream>>>(fbuf, Wv, bv, vbuf);
    atlas_np_k    <<<1024, 256, 0, stream>>>(vbuf, cc, cb, sfW1, sfb1, sfW2, sfb2, out, partials);
    loss_reduce_k <<<1, 256, 0, stream>>>(partials, out);
}

// Round 5
// 203.982 us; speedup vs baseline: 1.1090x; 1.1090x over previous
//
#include <hip/hip_runtime.h>
#include <hip/hip_bf16.h>

// Problem constants: B=32768, IN=64, H=256, D=16, C=8, K=64, HS=8
// Output layout (floats, concatenated in return order):
#define O0 0ull          // K_chart   [32768]
#define O1 32768ull      // K_code    [32768]
#define O2 65536ull      // z_n       [32768][16]
#define O3 589824ull     // z_tex     [32768][16]
#define O4 1114112ull    // router_weights [32768][8]
#define O5 1376256ull    // z_geo     [32768][16]
#define O6 1900544ull    // vq_loss   [1]
#define O7 1900545ull    // indices   [32768][8]
#define O8 2162689ull    // z_n_all_charts [32768][8][16]
#define O9 6356993ull    // c_bar     [32768][16]

// np-f32 gelu replica: x * (erf(x / f32(sqrt(2))) + 1) / 2, erf via double downcast
__device__ __forceinline__ float gelu_np(float x) {
#pragma clang fp contract(off)
    float t = x / 0x1.6a09e6p+0f;          // f32(sqrt(2))
    float e = (float)erf((double)t);
    float u = e + 1.0f;
    return (x * u) / 2.0f;
}

// Fused MLP: v = (gelu(gelu(x@W1+b1)@W2+b2))@Wv + bv, np-f32 replica.
// 32 rows/block, 256 threads (4 waves x 8 rows). f1/f2 in a padded LDS tile.
// All dot products: ascending-k sequential fmaf chain, bias added after
// (bit-identical to the round-4 passing kernels).
__global__ __launch_bounds__(256) void fused_mlp_np_k(
    const float* __restrict__ x,  const float* __restrict__ W1,
    const float* __restrict__ b1, const float* __restrict__ W2,
    const float* __restrict__ b2, const float* __restrict__ Wv,
    const float* __restrict__ bv, float* __restrict__ vout)
{
#pragma clang fp contract(off)
    __shared__ float ft[32][260];     // pad 4: phase-C bank spread, float4-aligned
    const int t  = threadIdx.x;
    const int w  = t >> 6;
    const int cg = t & 63;
    const int r0 = blockIdx.x * 32;
    const int rb = w * 8;             // wave's first row

    float acc[8][4];
#pragma unroll
    for (int i = 0; i < 8; ++i) { acc[i][0]=0.f; acc[i][1]=0.f; acc[i][2]=0.f; acc[i][3]=0.f; }

    // ---- phase A: f1 = gelu(x @ W1 + b1), K=64 ----
    for (int k0 = 0; k0 < 64; k0 += 4) {
        float4 w0 = *(const float4*)(W1 + (size_t)(k0 + 0) * 256 + cg * 4);
        float4 w1 = *(const float4*)(W1 + (size_t)(k0 + 1) * 256 + cg * 4);
        float4 w2 = *(const float4*)(W1 + (size_t)(k0 + 2) * 256 + cg * 4);
        float4 w3 = *(const float4*)(W1 + (size_t)(k0 + 3) * 256 + cg * 4);
#pragma unroll
        for (int rr = 0; rr < 8; ++rr) {
            float4 a = *(const float4*)(x + (size_t)(r0 + rb + rr) * 64 + k0);
            acc[rr][0] = fmaf(a.x, w0.x, acc[rr][0]);
            acc[rr][1] = fmaf(a.x, w0.y, acc[rr][1]);
            acc[rr][2] = fmaf(a.x, w0.z, acc[rr][2]);
            acc[rr][3] = fmaf(a.x, w0.w, acc[rr][3]);
            acc[rr][0] = fmaf(a.y, w1.x, acc[rr][0]);
            acc[rr][1] = fmaf(a.y, w1.y, acc[rr][1]);
            acc[rr][2] = fmaf(a.y, w1.z, acc[rr][2]);
            acc[rr][3] = fmaf(a.y, w1.w, acc[rr][3]);
            acc[rr][0] = fmaf(a.z, w2.x, acc[rr][0]);
            acc[rr][1] = fmaf(a.z, w2.y, acc[rr][1]);
            acc[rr][2] = fmaf(a.z, w2.z, acc[rr][2]);
            acc[rr][3] = fmaf(a.z, w2.w, acc[rr][3]);
            acc[rr][0] = fmaf(a.w, w3.x, acc[rr][0]);
            acc[rr][1] = fmaf(a.w, w3.y, acc[rr][1]);
            acc[rr][2] = fmaf(a.w, w3.z, acc[rr][2]);
            acc[rr][3] = fmaf(a.w, w3.w, acc[rr][3]);
        }
    }
    {
        float4 bb = *(const float4*)(b1 + cg * 4);
#pragma unroll
        for (int rr = 0; rr < 8; ++rr) {
            float4 o;
            o.x = gelu_np(acc[rr][0] + bb.x);
            o.y = gelu_np(acc[rr][1] + bb.y);
            o.z = gelu_np(acc[rr][2] + bb.z);
            o.w = gelu_np(acc[rr][3] + bb.w);
            *(float4*)&ft[rb + rr][cg * 4] = o;
        }
    }
    // no barrier: each wave reads only its own 8 rows next

    // ---- phase B: f2 = gelu(f1 @ W2 + b2), K=256 ----
#pragma unroll
    for (int i = 0; i < 8; ++i) { acc[i][0]=0.f; acc[i][1]=0.f; acc[i][2]=0.f; acc[i][3]=0.f; }
    for (int k0 = 0; k0 < 256; k0 += 4) {
        float4 w0 = *(const float4*)(W2 + (size_t)(k0 + 0) * 256 + cg * 4);
        float4 w1 = *(const float4*)(W2 + (size_t)(k0 + 1) * 256 + cg * 4);
        float4 w2 = *(const float4*)(W2 + (size_t)(k0 + 2) * 256 + cg * 4);
        float4 w3 = *(const float4*)(W2 + (size_t)(k0 + 3) * 256 + cg * 4);
#pragma unroll
        for (int rr = 0; rr < 8; ++rr) {
            float4 a = *(const float4*)&ft[rb + rr][k0];   // broadcast ds_read_b128
            acc[rr][0] = fmaf(a.x, w0.x, acc[rr][0]);
            acc[rr][1] = fmaf(a.x, w0.y, acc[rr][1]);
            acc[rr][2] = fmaf(a.x, w0.z, acc[rr][2]);
            acc[rr][3] = fmaf(a.x, w0.w, acc[rr][3]);
            acc[rr][0] = fmaf(a.y, w1.x, acc[rr][0]);
            acc[rr][1] = fmaf(a.y, w1.y, acc[rr][1]);
            acc[rr][2] = fmaf(a.y, w1.z, acc[rr][2]);
            acc[rr][3] = fmaf(a.y, w1.w, acc[rr][3]);
            acc[rr][0] = fmaf(a.z, w2.x, acc[rr][0]);
            acc[rr][1] = fmaf(a.z, w2.y, acc[rr][1]);
            acc[rr][2] = fmaf(a.z, w2.z, acc[rr][2]);
            acc[rr][3] = fmaf(a.z, w2.w, acc[rr][3]);
            acc[rr][0] = fmaf(a.w, w3.x, acc[rr][0]);
            acc[rr][1] = fmaf(a.w, w3.y, acc[rr][1]);
            acc[rr][2] = fmaf(a.w, w3.z, acc[rr][2]);
            acc[rr][3] = fmaf(a.w, w3.w, acc[rr][3]);
        }
    }
    __syncthreads();   // ft still holds f1 for other waves until here? No --
                       // each wave overwrites only its OWN rows below; barrier
                       // protects nothing yet but keeps waves phase-aligned.
    {
        float4 bb = *(const float4*)(b2 + cg * 4);
#pragma unroll
        for (int rr = 0; rr < 8; ++rr) {
            float4 o;
            o.x = gelu_np(acc[rr][0] + bb.x);
            o.y = gelu_np(acc[rr][1] + bb.y);
            o.z = gelu_np(acc[rr][2] + bb.z);
            o.w = gelu_np(acc[rr][3] + bb.w);
            *(float4*)&ft[rb + rr][cg * 4] = o;
        }
    }
    __syncthreads();   // phase C reads rows across waves

    // ---- phase C: v = f2 @ Wv + bv (ascending-k scalar chain per (row,d)) ----
    {
        const int vrow = t & 31;
        const int d0   = (t >> 5) * 2;
        float a0 = 0.f, a1 = 0.f;
        for (int k4 = 0; k4 < 256; k4 += 4) {
            float4 f = *(const float4*)&ft[vrow][k4];
            float2 q0 = *(const float2*)(Wv + (size_t)(k4 + 0) * 16 + d0);
            float2 q1 = *(const float2*)(Wv + (size_t)(k4 + 1) * 16 + d0);
            float2 q2 = *(const float2*)(Wv + (size_t)(k4 + 2) * 16 + d0);
            float2 q3 = *(const float2*)(Wv + (size_t)(k4 + 3) * 16 + d0);
            a0 = fmaf(f.x, q0.x, a0);  a1 = fmaf(f.x, q0.y, a1);
            a0 = fmaf(f.y, q1.x, a0);  a1 = fmaf(f.y, q1.y, a1);
            a0 = fmaf(f.z, q2.x, a0);  a1 = fmaf(f.z, q2.y, a1);
            a0 = fmaf(f.w, q3.x, a0);  a1 = fmaf(f.w, q3.y, a1);
        }
        float2 o = make_float2(a0 + bv[d0], a1 + bv[d0 + 1]);
        *(float2*)&vout[(size_t)(r0 + vrow) * 16 + d0] = o;
    }
}

// Per-row atlas, np-f32 replica arithmetic. thread=(row,chart), 32 rows/block.
__global__ __launch_bounds__(256) void atlas_np_k(
    const float* __restrict__ vbuf, const float* __restrict__ cc,
    const float* __restrict__ cb,   const float* __restrict__ sfW1,
    const float* __restrict__ sfb1, const float* __restrict__ sfW2,
    const float* __restrict__ sfb2, float* __restrict__ out,
    float* __restrict__ partials)
{
#pragma clang fp contract(off)
    __shared__ float scb[8 * 1284];   // (c,kk,d) at c*1284 + kk*20 + d
    __shared__ float scc[128];
    __shared__ float sW1[128];
    __shared__ float sW2[128];
    __shared__ float sb1[8];
    __shared__ float sb2[16];
    __shared__ float red[4];

    const int t = threadIdx.x;
    for (int i = t; i < 8192; i += 256) {
        int c = i >> 10, rem = i & 1023, kk = rem >> 4, d = rem & 15;
        scb[c * 1284 + kk * 20 + d] = cb[i];
    }
    if (t < 128) { scc[t] = cc[t]; sW1[t] = sfW1[t]; sW2[t] = sfW2[t]; }
    if (t < 8)  sb1[t] = sfb1[t];
    if (t < 16) sb2[t] = sfb2[t];
    __syncthreads();

    const int c    = t & 7;
    const int lane = t & 63;
    const int lb   = lane & ~7;
    const int row  = blockIdx.x * 32 + (t >> 3);

    float v[16];
    {
        const float4* vp = (const float4*)(vbuf + (size_t)row * 16);
        float4 a = vp[0], b = vp[1], g = vp[2], h4 = vp[3];
        v[0]=a.x;  v[1]=a.y;  v[2]=a.z;  v[3]=a.w;
        v[4]=b.x;  v[5]=b.y;  v[6]=b.z;  v[7]=b.w;
        v[8]=g.x;  v[9]=g.y;  v[10]=g.z; v[11]=g.w;
        v[12]=h4.x; v[13]=h4.y; v[14]=h4.z; v[15]=h4.w;
    }

    // scores: sgemm k-seq fma over d, then /4 (exact)
    float score = 0.f;
#pragma unroll
    for (int d = 0; d < 16; ++d) score = fmaf(v[d], scc[c * 16 + d], score);
    score = score / 4.0f;

    // softmax: max (exact), exp via double downcast, pairwise-8 scalar-tree sum
    float m = score;
#pragma unroll
    for (int off = 1; off < 8; off <<= 1) m = fmaxf(m, __shfl_xor(m, off));
    float e = (float)exp((double)(score - m));
    float ea[8];
#pragma unroll
    for (int j = 0; j < 8; ++j) ea[j] = __shfl(e, lb + j);
    float s = ((ea[0] + ea[1]) + (ea[2] + ea[3])) + ((ea[4] + ea[5]) + (ea[6] + ea[7]));
    float rw = e / s;

    float rwa[8];
#pragma unroll
    for (int j = 0; j < 8; ++j) rwa[j] = ea[j] / s;

    // K_chart = np.argmax(router_weights): first-wins scan on f32 rw
    float bmv = rwa[0]; int bci = 0;
#pragma unroll
    for (int j = 1; j < 8; ++j) if (rwa[j] > bmv) { bmv = rwa[j]; bci = j; }

    // c_bar: sgemm K=8 seq fma; v_local f32 sub
    float cbar[16], vl[16];
#pragma unroll
    for (int d = 0; d < 16; ++d) {
        float a = 0.f;
#pragma unroll
        for (int j = 0; j < 8; ++j) a = fmaf(rwa[j], scc[j * 16 + d], a);
        cbar[d] = a;
        vl[d]   = v[d] - a;
    }

    // argmin over 64 codes: np dist = pairwise-16 scalar tree of (vl-q)^2, no fma
    const float* cbc = scb + c * 1284;
    float bd = 3.4e38f; int bk = 0; bool first = true;
    for (int kk = 0; kk < 64; ++kk) {
        const float4* q = (const float4*)(cbc + kk * 20);
        float4 q0 = q[0], q1 = q[1], q2 = q[2], q3 = q[3];
        float sq[16];
        float dd;
        dd = vl[0]  - q0.x; sq[0]  = dd * dd;
        dd = vl[1]  - q0.y; sq[1]  = dd * dd;
        dd = vl[2]  - q0.z; sq[2]  = dd * dd;
        dd = vl[3]  - q0.w; sq[3]  = dd * dd;
        dd = vl[4]  - q1.x; sq[4]  = dd * dd;
        dd = vl[5]  - q1.y; sq[5]  = dd * dd;
        dd = vl[6]  - q1.z; sq[6]  = dd * dd;
        dd = vl[7]  - q1.w; sq[7]  = dd * dd;
        dd = vl[8]  - q2.x; sq[8]  = dd * dd;
        dd = vl[9]  - q2.y; sq[9]  = dd * dd;
        dd = vl[10] - q2.z; sq[10] = dd * dd;
        dd = vl[11] - q2.w; sq[11] = dd * dd;
        dd = vl[12] - q3.x; sq[12] = dd * dd;
        dd = vl[13] - q3.y; sq[13] = dd * dd;
        dd = vl[14] - q3.z; sq[14] = dd * dd;
        dd = vl[15] - q3.w; sq[15] = dd * dd;
        float r0_ = sq[0] + sq[8],  r1_ = sq[1] + sq[9];
        float r2_ = sq[2] + sq[10], r3_ = sq[3] + sq[11];
        float r4_ = sq[4] + sq[12], r5_ = sq[5] + sq[13];
        float r6_ = sq[6] + sq[14], r7_ = sq[7] + sq[15];
        float dist = ((r0_ + r1_) + (r2_ + r3_)) + ((r4_ + r5_) + (r6_ + r7_));
        if (first || dist < bd) { bd = dist; bk = kk; first = false; }
    }

    float zq[16];
    {
        const float4* q = (const float4*)(cbc + bk * 20);
        float4 q0 = q[0], q1 = q[1], q2 = q[2], q3 = q[3];
        zq[0]=q0.x;  zq[1]=q0.y;  zq[2]=q0.z;  zq[3]=q0.w;
        zq[4]=q1.x;  zq[5]=q1.y;  zq[6]=q1.z;  zq[7]=q1.w;
        zq[8]=q2.x;  zq[9]=q2.y;  zq[10]=q2.z; zq[11]=q2.w;
        zq[12]=q3.x; zq[13]=q3.y; zq[14]=q3.z; zq[15]=q3.w;
    }

    float del[16];
#pragma unroll
    for (int d = 0; d < 16; ++d) del[d] = vl[d] - zq[d];

    // subnet: sgemm k-seq fma + bias-after + gelu_np, then K=8 fma + bias
    float h[8];
#pragma unroll
    for (int j = 0; j < 8; ++j) {
        float a = 0.f;
#pragma unroll
        for (int d = 0; d < 16; ++d) a = fmaf(del[d], sW1[d * 8 + j], a);
        h[j] = gelu_np(a + sb1[j]);
    }
    float zn[16];
#pragma unroll
    for (int d = 0; d < 16; ++d) {
        float a = 0.f;
#pragma unroll
        for (int j = 0; j < 8; ++j) a = fmaf(h[j], sW2[j * 16 + d], a);
        zn[d] = a + sb2[d];
    }

    // loss: rw * ||vl - zq||^2 (threshold loose; any order)
    float ls = 0.f;
#pragma unroll
    for (int d = 0; d < 16; ++d) ls = fmaf(del[d], del[d], ls);
    ls *= rw;

    // cross-chart sums: np sum over axis=1 (outer axis) = SEQUENTIAL over c,
    // products rounded first. Gather via shuffles; every lane computes all 16.
    float zqb[16], zns[16];
#pragma unroll
    for (int dd = 0; dd < 16; ++dd) {
        float aq = 0.f, an = 0.f;
#pragma unroll
        for (int j = 0; j < 8; ++j) {
            float qv = __shfl(zq[dd], lb + j);
            float nv = __shfl(zn[dd], lb + j);
            float pq = qv * rwa[j];
            float pn = nv * rwa[j];
            aq = aq + pq;
            an = an + pn;
        }
        zqb[dd] = aq;
        zns[dd] = an;
    }

    // stores
    out[O4 + (size_t)row * 8 + c] = rw;
    out[O7 + (size_t)row * 8 + c] = (float)bk;
    {
        float* p = out + O8 + (size_t)row * 128 + c * 16;
#pragma unroll
        for (int d = 0; d < 16; ++d) p[d] = zn[d];
    }
    if (c == 0)   out[O0 + row] = (float)bci;
    if (c == bci) out[O1 + row] = (float)bk;
#pragma unroll
    for (int u = 0; u < 2; ++u) {
        int d = c * 2 + u;
        float zst = vl[d] + (zqb[d] - vl[d]);           // z_q_st np order
        out[O2 + (size_t)row * 16 + d] = zns[d];                    // z_n
        out[O3 + (size_t)row * 16 + d] = (vl[d] - zqb[d]) - zns[d]; // z_tex
        out[O5 + (size_t)row * 16 + d] = (cbar[d] + zst) + zns[d];  // z_geo
        out[O9 + (size_t)row * 16 + d] = cbar[d];                   // c_bar
    }

    // block loss partial (deterministic)
#pragma unroll
    for (int off = 1; off < 64; off <<= 1) ls += __shfl_xor(ls, off);
    if ((t & 63) == 0) red[t >> 6] = ls;
    __syncthreads();
    if (t == 0) partials[blockIdx.x] = red[0] + red[1] + red[2] + red[3];
}

__global__ __launch_bounds__(256) void loss_reduce_k(
    const float* __restrict__ partials, float* __restrict__ out)
{
    __shared__ float sm[256];
    const int t = threadIdx.x;
    float a = 0.f;
    for (int i = t; i < 1024; i += 256) a += partials[i];
    sm[t] = a;
    __syncthreads();
    for (int s2 = 128; s2 > 0; s2 >>= 1) {
        if (t < s2) sm[t] += sm[t + s2];
        __syncthreads();
    }
    if (t == 0) out[O6] = sm[0] * (1.25f / 524288.0f);  // 1.25 / (B*D)
}

extern "C" void kernel_launch(void* const* d_in, const int* in_sizes, int n_in,
                              void* d_out, int out_size, void* d_ws, size_t ws_size,
                              hipStream_t stream) {
    (void)in_sizes; (void)n_in; (void)out_size;
    const float* x    = (const float*)d_in[0];
    const float* W1   = (const float*)d_in[1];
    const float* b1   = (const float*)d_in[2];
    const float* W2   = (const float*)d_in[3];
    const float* b2   = (const float*)d_in[4];
    const float* Wv   = (const float*)d_in[5];
    const float* bv   = (const float*)d_in[6];
    const float* cc   = (const float*)d_in[7];
    const float* cb   = (const float*)d_in[8];
    const float* sfW1 = (const float*)d_in[9];
    const float* sfb1 = (const float*)d_in[10];
    const float* sfW2 = (const float*)d_in[11];
    const float* sfb2 = (const float*)d_in[12];
    float* out = (float*)d_out;

    float* vbuf = (float*)d_ws;                       // [32768][16] f32 (2 MB)
    float* partials = vbuf + (size_t)32768 * 16;      // [1024]
    if (ws_size < ((size_t)32768 * 16 + 1024) * 4) return;

    fused_mlp_np_k<<<1024, 256, 0, stream>>>(x, W1, b1, W2, b2, Wv, bv, vbuf);
    atlas_np_k    <<<1024, 256, 0, stream>>>(vbuf, cc, cb, sfW1, sfb1, sfW2, sfb2, out, partials);
    loss_reduce_k <<<1, 256, 0, stream>>>(partials, out);
}